// Round 8
// baseline (127.767 us; speedup 1.0000x reference)
//
#include <hip/hip_runtime.h>
#include <hip/hip_bf16.h>

// BlurDownsample: depthwise 4x4 FIR (separable taps [1,3,3,1]/8 per axis),
// stride-2 downsample, pad (1,1). x: [N,C,256,256] f32 -> y: [N,C,128,128] f32.
//
// R8 = R7 hot loop, with scheduling fixes:
//  - grid = 1024 blocks x 2 planes each, 4 blocks/CU, ALL co-resident in one
//    round -> removes the 1.33-round block quantization tail of R7 (2048
//    blocks over ~1536 slots).
//  - __launch_bounds__(256, 4): VGPR cap 128, load train fully outstanding.
//  - tile-boundary rows (first 2 / last 2 per wave-tile) use REGULAR loads:
//    they're shared with the neighboring wave in the SAME block (same CU,
//    concurrent) -> L1/L2 hit. Interior 62 rows stay nontemporal.
//  - wave-per-row float4 loads + shfl neighbor exchange, branch-free padding,
//    rolling 4-scalar h-window, unroll 8, nontemporal float2 stores.

constexpr int H  = 256;
constexpr int W  = 256;
constexpr int OH = 128;
constexpr int OW = 128;
constexpr int WAVES_PER_BLOCK = 4;           // 256 threads
constexpr int TILE = OH / WAVES_PER_BLOCK;   // 32 output rows per wave
constexpr int PLANES_PER_BLOCK = 2;

typedef float f32x2 __attribute__((ext_vector_type(2)));
typedef float f32x4 __attribute__((ext_vector_type(4)));

__global__ __launch_bounds__(256, 4) void blur_down_kernel(
    const float* __restrict__ x, float* __restrict__ y) {
    const int wave  = threadIdx.x >> 6;
    const int lane  = threadIdx.x & 63;

    const int oh0 = wave * TILE;             // first output row of this wave
    const int r0  = 2 * oh0 - 1;             // first input row of the window

    const float mL = (lane == 0)  ? 0.0f : 1.0f;  // col -1 zero pad
    const float mR = (lane == 63) ? 0.0f : 1.0f;  // col 256 zero pad

    for (int i = 0; i < PLANES_PER_BLOCK; ++i) {
        const int plane = blockIdx.x * PLANES_PER_BLOCK + i;
        const float* __restrict__ xp = x + (size_t)plane * H * W + lane * 4;
        float* __restrict__ yp = y + (size_t)plane * OH * OW + 2 * lane;

        // horizontal FIR on an already-loaded row vector
        // he (ow=2t)   = x[4t-1] + 3x[4t]   + 3x[4t+1] + x[4t+2]
        // ho (ow=2t+1) = x[4t+1] + 3x[4t+2] + 3x[4t+3] + x[4t+4]
        auto hfir = [&](const f32x4& v, float& he, float& ho) {
            const float xm1 = __shfl_up(v.w, 1) * mL;   // col 4t-1
            const float xp4 = __shfl_down(v.x, 1) * mR; // col 4t+4
            he = (xm1 + v.z) + 3.0f * (v.x + v.y);
            ho = (v.y + xp4) + 3.0f * (v.z + v.w);
        };

        // interior rows: nontemporal (read exactly once, evict-first)
        auto hrow_nt = [&](int r, float& he, float& ho) {
            const f32x4 v = __builtin_nontemporal_load(
                reinterpret_cast<const f32x4*>(xp + (size_t)r * W));
            hfir(v, he, ho);
        };
        // boundary rows: regular load (shared with neighbor wave -> cache hit)
        auto hrow_reg = [&](int r, float& he, float& ho) {
            const f32x4 v = *reinterpret_cast<const f32x4*>(xp + (size_t)r * W);
            hfir(v, he, ho);
        };
        // clamped+masked edge row (may be out of [0,H))
        auto hrow_m = [&](int r, float& he, float& ho) {
            const int rc  = min(max(r, 0), H - 1);
            const float m = (r == rc) ? 1.0f : 0.0f;
            const f32x4 v = *reinterpret_cast<const f32x4*>(xp + (size_t)rc * W);
            hfir(v, he, ho);
            he *= m; ho *= m;
        };

        // prologue rows r0, r0+1: r0 clamps only for wave 0; both boundary
        float h0e, h0o, h1e, h1o;
        hrow_m(r0, h0e, h0o);
        hrow_reg(r0 + 1, h1e, h1o);

        // main loop: rows r0+2 .. r0+63 are in [1, 253] -> unconditional nt
        #pragma unroll 8
        for (int k = 0; k < TILE - 1; ++k) {
            float h2e, h2o, h3e, h3o;
            hrow_nt(r0 + 2 * k + 2, h2e, h2o);
            hrow_nt(r0 + 2 * k + 3, h3e, h3o);
            f32x2 out;
            out.x = ((h0e + h3e) + 3.0f * (h1e + h2e)) * (1.0f / 64.0f);
            out.y = ((h0o + h3o) + 3.0f * (h1o + h2o)) * (1.0f / 64.0f);
            __builtin_nontemporal_store(
                out, reinterpret_cast<f32x2*>(yp + (size_t)(oh0 + k) * OW));
            h0e = h2e; h0o = h2o;
            h1e = h3e; h1o = h3o;
        }
        // epilogue rows r0+64, r0+65: boundary; r0+65 is 256 for wave 3
        {
            const int k = TILE - 1;
            float h2e, h2o, h3e, h3o;
            hrow_reg(r0 + 2 * k + 2, h2e, h2o);
            hrow_m(r0 + 2 * k + 3, h3e, h3o);
            f32x2 out;
            out.x = ((h0e + h3e) + 3.0f * (h1e + h2e)) * (1.0f / 64.0f);
            out.y = ((h0o + h3o) + 3.0f * (h1o + h2o)) * (1.0f / 64.0f);
            __builtin_nontemporal_store(
                out, reinterpret_cast<f32x2*>(yp + (size_t)(oh0 + k) * OW));
        }
    }
}

extern "C" void kernel_launch(void* const* d_in, const int* in_sizes, int n_in,
                              void* d_out, int out_size, void* d_ws, size_t ws_size,
                              hipStream_t stream) {
    const float* x = (const float*)d_in[0];
    float* y = (float*)d_out;

    const int planes = in_sizes[0] / (H * W);          // N*C = 2048
    const int grid   = planes / PLANES_PER_BLOCK;      // 1024 blocks
    hipLaunchKernelGGL(blur_down_kernel, dim3(grid), dim3(256), 0, stream,
                       x, y);
}

// Round 9
// 121.366 us; speedup vs baseline: 1.0527x; 1.0527x over previous
//
#include <hip/hip_runtime.h>
#include <hip/hip_bf16.h>

// BlurDownsample: depthwise 4x4 FIR (separable taps [1,3,3,1]/8 per axis),
// stride-2 downsample, pad (1,1). x: [N,C,256,256] f32 -> y: [N,C,128,128] f32.
//
// R9 = R7 (best: 121.0us) + boundary-row cache fix from R8:
//  - 2048 blocks, 1 plane each, __launch_bounds__(256, 6): 24 waves/CU.
//    (R8 showed occupancy >> tail: 4 blocks/CU one-round config regressed.)
//  - tile-boundary rows (first/last 2 per wave-tile, shared with the
//    concurrent neighbor wave in the same block) use REGULAR loads -> L1/L2
//    hit for the second reader. Interior 62 rows stay nontemporal.
//  - wave-per-row float4 loads + shfl neighbor exchange, branch-free padding,
//    rolling 4-scalar h-window, unroll 8, nontemporal float2 stores.

constexpr int H  = 256;
constexpr int W  = 256;
constexpr int OH = 128;
constexpr int OW = 128;
constexpr int WAVES_PER_BLOCK = 4;           // 256 threads
constexpr int TILE = OH / WAVES_PER_BLOCK;   // 32 output rows per wave

typedef float f32x2 __attribute__((ext_vector_type(2)));
typedef float f32x4 __attribute__((ext_vector_type(4)));

__global__ __launch_bounds__(256, 6) void blur_down_kernel(
    const float* __restrict__ x, float* __restrict__ y) {
    const int plane = blockIdx.x;
    const int wave  = threadIdx.x >> 6;
    const int lane  = threadIdx.x & 63;

    const float* __restrict__ xp = x + (size_t)plane * H * W + lane * 4;
    float* __restrict__ yp       = y + (size_t)plane * OH * OW + 2 * lane;

    const int oh0 = wave * TILE;             // first output row of this wave
    const int r0  = 2 * oh0 - 1;             // first input row of the window

    const float mL = (lane == 0)  ? 0.0f : 1.0f;  // col -1 zero pad
    const float mR = (lane == 63) ? 0.0f : 1.0f;  // col 256 zero pad

    // horizontal FIR on an already-loaded row vector
    // he (ow=2t)   = x[4t-1] + 3x[4t]   + 3x[4t+1] + x[4t+2]
    // ho (ow=2t+1) = x[4t+1] + 3x[4t+2] + 3x[4t+3] + x[4t+4]
    auto hfir = [&](const f32x4& v, float& he, float& ho) {
        const float xm1 = __shfl_up(v.w, 1) * mL;   // col 4t-1
        const float xp4 = __shfl_down(v.x, 1) * mR; // col 4t+4
        he = (xm1 + v.z) + 3.0f * (v.x + v.y);
        ho = (v.y + xp4) + 3.0f * (v.z + v.w);
    };

    // interior rows: nontemporal (read exactly once on this CU, evict-first)
    auto hrow_nt = [&](int r, float& he, float& ho) {
        const f32x4 v = __builtin_nontemporal_load(
            reinterpret_cast<const f32x4*>(xp + (size_t)r * W));
        hfir(v, he, ho);
    };
    // boundary rows: regular load (read twice within the block -> cache hit)
    auto hrow_reg = [&](int r, float& he, float& ho) {
        const f32x4 v = *reinterpret_cast<const f32x4*>(xp + (size_t)r * W);
        hfir(v, he, ho);
    };
    // clamped+masked edge row (may be out of [0,H))
    auto hrow_m = [&](int r, float& he, float& ho) {
        const int rc  = min(max(r, 0), H - 1);
        const float m = (r == rc) ? 1.0f : 0.0f;
        const f32x4 v = *reinterpret_cast<const f32x4*>(xp + (size_t)rc * W);
        hfir(v, he, ho);
        he *= m; ho *= m;
    };

    // prologue rows r0, r0+1: r0 clamps only for wave 0; both are boundary
    float h0e, h0o, h1e, h1o;
    hrow_m(r0, h0e, h0o);
    hrow_reg(r0 + 1, h1e, h1o);

    // main loop: rows r0+2 .. r0+63 are in [1, 253] -> unconditional nt
    #pragma unroll 8
    for (int k = 0; k < TILE - 1; ++k) {
        float h2e, h2o, h3e, h3o;
        hrow_nt(r0 + 2 * k + 2, h2e, h2o);
        hrow_nt(r0 + 2 * k + 3, h3e, h3o);
        f32x2 out;
        out.x = ((h0e + h3e) + 3.0f * (h1e + h2e)) * (1.0f / 64.0f);
        out.y = ((h0o + h3o) + 3.0f * (h1o + h2o)) * (1.0f / 64.0f);
        __builtin_nontemporal_store(
            out, reinterpret_cast<f32x2*>(yp + (size_t)(oh0 + k) * OW));
        h0e = h2e; h0o = h2o;
        h1e = h3e; h1o = h3o;
    }
    // epilogue rows r0+64, r0+65: boundary; r0+65 is 256 for wave 3
    {
        const int k = TILE - 1;
        float h2e, h2o, h3e, h3o;
        hrow_reg(r0 + 2 * k + 2, h2e, h2o);
        hrow_m(r0 + 2 * k + 3, h3e, h3o);
        f32x2 out;
        out.x = ((h0e + h3e) + 3.0f * (h1e + h2e)) * (1.0f / 64.0f);
        out.y = ((h0o + h3o) + 3.0f * (h1o + h2o)) * (1.0f / 64.0f);
        __builtin_nontemporal_store(
            out, reinterpret_cast<f32x2*>(yp + (size_t)(oh0 + k) * OW));
    }
}

extern "C" void kernel_launch(void* const* d_in, const int* in_sizes, int n_in,
                              void* d_out, int out_size, void* d_ws, size_t ws_size,
                              hipStream_t stream) {
    const float* x = (const float*)d_in[0];
    float* y = (float*)d_out;

    const int planes = in_sizes[0] / (H * W);   // N*C = 2048
    hipLaunchKernelGGL(blur_down_kernel, dim3(planes), dim3(256), 0, stream,
                       x, y);
}